// Round 2
// baseline (380.245 us; speedup 1.0000x reference)
//
#include <hip/hip_runtime.h>

// Problem dims (fixed by setup_inputs)
#define NODES 8192
#define DIM   200
#define NEDGE 4096
#define DEGREE 16
#define HD    128
#define MT    8      // rows per tile -> 1024 tiles
#define ECAP  32     // per-node edge-list stride (Poisson(8); P(>32) ~ 1e-11/node)
#define NBLK  512    // half of HW capacity (4/CU * 256 CU) -> co-residency guaranteed
#define NTILE (NODES / MT)   // 1024

struct Params {
    const float *x, *text, *W, *bias, *gate_w, *gate_b, *gnn_w, *gnn_b,
                *text_w, *text_b, *in_w, *in_b, *aow, *aob, *fgw, *fgb,
                *opw, *opb;
    const int  *en;
    float *out;
    // scratch
    int   *bar;     // [4] grid-barrier arrival counters (memset to 0 each launch)
    int   *cnt;     // [NODES] unique-incidence count (zeroed in phase B)
    float *cpart;   // [256][DIM] atomic-free colsum partials
    float *out2;    // [NODES][HD] x @ (W@gnn_w)
    float *tE;      // [NEDGE][HD]
    int   *elist2;  // [NODES][ECAP]
    float *Wg;      // [DIM][HD]
    float *alpha;   // [1]
    float *bg;      // [HD]
    float *attO;    // [4][HD]
    float *attg;    // [4][HD]
    int   *emask;   // [NEDGE]
};

__device__ __forceinline__ float dv_of(int cnt) {
    return 1.0f / sqrtf((float)cnt * (1.0f / 16.0f) + 1e-8f);
}

// Grid barrier: one fresh counter per sync point. RELEASE arrival publishes all
// prior stores (agent scope -> L2 writeback past the non-coherent per-XCD L2s);
// acquire side via __threadfence() after the spin invalidates L1/L2 so
// subsequent plain loads fetch fresh data. Normal launch, no hidden runtime args.
__device__ __forceinline__ void gbar(int* bar, int idx) {
    __syncthreads();
    if (threadIdx.x == 0) {
        __hip_atomic_fetch_add(&bar[idx], 1, __ATOMIC_RELEASE, __HIP_MEMORY_SCOPE_AGENT);
        while (__hip_atomic_load(&bar[idx], __ATOMIC_RELAXED, __HIP_MEMORY_SCOPE_AGENT) < NBLK)
            __builtin_amdgcn_s_sleep(2);
    }
    __syncthreads();
    __threadfence();
}

__global__ __launch_bounds__(256, 4) void k_fused(Params p) {
    __shared__ __align__(16) union SM {
        float sx[MT * DIM];                                              // phase C tile
        struct { float st[DIM]; float part[2][HD]; float vin[HD]; } tx;  // phase B text
        struct { float sgp[MT][HD]; int sid[MT][ECAP]; int scount[MT]; } tl; // phase E
    } sm;
    __shared__ float red[256];
    const int b = blockIdx.x, t = threadIdx.x;

    // ===== phase B: zero cnt + colsum partials + Wg + bg + text path =====
    if (t < 16) p.cnt[b * 16 + t] = 0;               // 512*16 == NODES
    if (b < 256) {                                   // atomic-free column-sum partials
        if (t < DIM) {
            float acc = 0.f;
            int r0 = b * 32;
            for (int r = 0; r < 32; r++) acc += p.x[(r0 + r) * DIM + t];
            p.cpart[b * DIM + t] = acc;
        }
    } else if (b < 356) {                            // Wg = W @ gnn_w, 2 rows/block
        int r = 2 * (b - 256) + (t >> 7), c = t & 127;
        const float* vec = &p.W[r * DIM];
        float acc = 0.f;
        for (int k = 0; k < DIM; k++) acc += vec[k] * p.gnn_w[k * HD + c];
        p.Wg[r * HD + c] = acc;
    } else if (b == 356) {                           // bg = bias @ gnn_w + gnn_b
        if (t < HD) {
            float acc = 0.f;
            for (int k = 0; k < DIM; k++) acc += p.bias[k] * p.gnn_w[k * HD + t];
            p.bg[t] = acc + p.gnn_b[t];
        }
    } else if (b < 361) {                            // text path, graph g (q/k/softmax dead)
        int g = b - 357;
        int c = t & 127, h = t >> 7;
        if (t < DIM) sm.tx.st[t] = p.text[g * DIM + t];
        __syncthreads();
        {   // tp = text @ text_w + text_b (k=200 split 100/100)
            float acc = 0.f;
            int k0 = h * 100;
            for (int k = k0; k < k0 + 100; k++) acc += sm.tx.st[k] * p.text_w[k * HD + c];
            sm.tx.part[h][c] = acc;
        }
        __syncthreads();
        if (t < HD) sm.tx.vin[t] = sm.tx.part[0][t] + sm.tx.part[1][t] + p.text_b[t];
        __syncthreads();
        {   // v = tp @ in_w[:, 2H:3H] + in_b[2H:3H]
            float acc = 0.f;
            int k0 = h * 64;
            for (int k = k0; k < k0 + 64; k++)
                acc += sm.tx.vin[k] * p.in_w[k * 3 * HD + 2 * HD + c];
            sm.tx.part[h][c] = acc;
        }
        __syncthreads();
        if (t < HD) sm.tx.vin[t] = sm.tx.part[0][t] + sm.tx.part[1][t] + p.in_b[2 * HD + t];
        __syncthreads();
        {   // attO = v @ aow + aob
            float acc = 0.f;
            int k0 = h * 64;
            for (int k = k0; k < k0 + 64; k++) acc += sm.tx.vin[k] * p.aow[k * HD + c];
            sm.tx.part[h][c] = acc;
        }
        __syncthreads();
        if (t < HD) {
            float ao = sm.tx.part[0][t] + sm.tx.part[1][t] + p.aob[t];
            p.attO[g * HD + t] = ao;
            sm.tx.vin[t] = ao;
        }
        __syncthreads();
        {   // attg = attO @ fgw[H:2H,:] + fgb
            float acc = 0.f;
            int k0 = h * 64;
            for (int k = k0; k < k0 + 64; k++) acc += sm.tx.vin[k] * p.fgw[(HD + k) * HD + c];
            sm.tx.part[h][c] = acc;
        }
        __syncthreads();
        if (t < HD) p.attg[g * HD + t] = sm.tx.part[0][t] + sm.tx.part[1][t] + p.fgb[t];
    }
    gbar(p.bar, 0);

    // ===== phase C: dedupe (8 edges/block) + out2 (2 tiles/block) + alpha =====
    if (t < 8) {
        int e = b * 8 + t;                           // 512*8 == NEDGE
        int idx[DEGREE];
#pragma unroll
        for (int i = 0; i < DEGREE; i++) idx[i] = p.en[e * DEGREE + i];
        int mask = 0;
#pragma unroll
        for (int i = 0; i < DEGREE; i++) {
            bool uniq = true;
            for (int j = 0; j < i; j++) uniq = uniq && (idx[j] != idx[i]);
            if (uniq) {
                mask |= (1 << i);
                int slot = atomicAdd(&p.cnt[idx[i]], 1);   // slot doubles as list index
                if (slot < ECAP) p.elist2[idx[i] * ECAP + slot] = e;
            }
        }
        p.emask[e] = mask;
    }
    for (int it = 0; it < 2; ++it) {
        int bm = (b + it * NBLK) * MT;               // tiles 0..1023
        const float4* x4 = (const float4*)(p.x + bm * DIM);
        float4* sx4 = (float4*)sm.sx;
        for (int i = t; i < MT * DIM / 4; i += 256) sx4[i] = x4[i];
        __syncthreads();
        int c = t & 127, rg = t >> 7;
        float acc[4] = {0.f, 0.f, 0.f, 0.f};
        for (int k = 0; k < DIM; k++) {
            float w = p.Wg[k * HD + c];
#pragma unroll
            for (int i = 0; i < 4; i++) acc[i] += sm.sx[(rg * 4 + i) * DIM + k] * w;
        }
#pragma unroll
        for (int i = 0; i < 4; i++) p.out2[(bm + rg * 4 + i) * HD + c] = acc[i];
        __syncthreads();                             // sx reused next iteration
    }
    if (b == 0) {   // alpha = sigmoid(mean(x) @ gate_w + gate_b) from partials
        float v = 0.f;
        if (t < DIM) {
            float s = 0.f;
            for (int q = 0; q < 256; q++) s += p.cpart[q * DIM + t];
            v = s * p.gate_w[t];
        }
        red[t] = v;
        __syncthreads();
        for (int o = 128; o > 0; o >>= 1) {
            if (t < o) red[t] += red[t + o];
            __syncthreads();
        }
        if (t == 0) {
            float z = red[0] / (float)NODES + p.gate_b[0];
            p.alpha[0] = 1.0f / (1.0f + expf(-z));
        }
    }
    gbar(p.bar, 1);

    // ===== phase D: tE[e,:] = de * sum_{uniq} dv*out2  (8 edges/block) =====
#pragma unroll
    for (int pass = 0; pass < 4; ++pass) {
        int e = b * 8 + pass * 2 + (t >> 7);
        int c = t & 127;
        int m = p.emask[e];
        float De = (float)__popc(m) * (1.0f / 16.0f);
        float de = 1.0f / (De + 1e-8f);
        int nd[DEGREE];
#pragma unroll
        for (int i = 0; i < DEGREE; i++) nd[i] = p.en[e * DEGREE + i];
        float acc = 0.f;
#pragma unroll
        for (int i = 0; i < DEGREE; i++)
            if ((m >> i) & 1) acc += dv_of(p.cnt[nd[i]]) * p.out2[nd[i] * HD + c];
        p.tE[e * HD + c] = de * acc;
    }
    gbar(p.bar, 2);

    // ===== phase E: fused tail, 2 tiles/block =====
    for (int it = 0; it < 2; ++it) {
        int bm = (b + it * NBLK) * MT;
        int gb = bm >> 11;               // graph id (tiles never straddle graphs)
        {   // stage per-row edge lists (32 threads/row)
            int r = t >> 5, sl = t & 31;
            int n = bm + r;
            int cc = p.cnt[n]; cc = cc < ECAP ? cc : ECAP;
            if (sl == 0) sm.tl.scount[r] = cc;
            if (sl < cc) sm.tl.sid[r][sl] = p.elist2[n * ECAP + sl];
        }
        __syncthreads();
        int c = t & 127, rg = t >> 7;
        float a = p.alpha[0];
        float bgc = p.bg[c];
#pragma unroll
        for (int i = 0; i < 4; i++) {    // gp rows into LDS
            int r = rg * 4 + i;
            int n = bm + r;
            int cc = sm.tl.scount[r];
            float hyp = 0.f;
            for (int j = 0; j < cc; j++) hyp += p.tE[sm.tl.sid[r][j] * HD + c];
            hyp *= dv_of(p.cnt[n]) * (1.0f / 256.0f);
            sm.tl.sgp[r][c] = a * p.out2[n * HD + c] + (1.0f - a) * hyp + bgc;
        }
        __syncthreads();
        float ao = p.attO[gb * HD + c];
        float ag = p.attg[gb * HD + c];
        float acc[4] = {ag, ag, ag, ag};
        for (int j = 0; j < HD; j++) {   // gate logits
            float w = p.fgw[j * HD + c];
#pragma unroll
            for (int i = 0; i < 4; i++) acc[i] += sm.tl.sgp[rg * 4 + i][j] * w;
        }
        __syncthreads();
#pragma unroll
        for (int i = 0; i < 4; i++) {    // fused = g*gp + (1-g)*attO
            int r = rg * 4 + i;
            float g = 1.0f / (1.0f + expf(-acc[i]));
            sm.tl.sgp[r][c] = g * sm.tl.sgp[r][c] + (1.0f - g) * ao;
        }
        __syncthreads();
        if (t < DIM) {                   // out = fused @ opw + opb
            float accO[MT];
            float ob = p.opb[t];
#pragma unroll
            for (int i = 0; i < MT; i++) accO[i] = ob;
            for (int j = 0; j < HD; j++) {
                float w = p.opw[j * DIM + t];
#pragma unroll
                for (int i = 0; i < MT; i++) accO[i] += sm.tl.sgp[i][j] * w;
            }
#pragma unroll
            for (int i = 0; i < MT; i++) p.out[(bm + i) * DIM + t] = accO[i];
        }
        __syncthreads();                 // LDS reused next iteration
    }
}

extern "C" void kernel_launch(void* const* d_in, const int* in_sizes, int n_in,
                              void* d_out, int out_size, void* d_ws, size_t ws_size,
                              hipStream_t stream) {
    Params P;
    P.x      = (const float*)d_in[0];
    P.text   = (const float*)d_in[1];
    P.W      = (const float*)d_in[2];
    P.bias   = (const float*)d_in[3];
    P.gate_w = (const float*)d_in[4];
    P.gate_b = (const float*)d_in[5];
    P.gnn_w  = (const float*)d_in[6];
    P.gnn_b  = (const float*)d_in[7];
    P.text_w = (const float*)d_in[8];
    P.text_b = (const float*)d_in[9];
    P.in_w   = (const float*)d_in[10];
    P.in_b   = (const float*)d_in[11];
    P.aow    = (const float*)d_in[12];
    P.aob    = (const float*)d_in[13];
    P.fgw    = (const float*)d_in[14];
    P.fgb    = (const float*)d_in[15];
    P.opw    = (const float*)d_in[16];
    P.opb    = (const float*)d_in[17];
    P.en     = (const int*)d_in[18];
    P.out    = (float*)d_out;

    // Scratch layout (~8 MB of d_ws). Only the 4 barrier ints need pre-zeroing;
    // cnt is zeroed in phase B, everything else fully overwritten before read.
    char* q = (char*)d_ws;
    P.bar    = (int*)q;   q += 4 * sizeof(int);
    P.cnt    = (int*)q;   q += NODES * sizeof(int);
    P.cpart  = (float*)q; q += 256 * DIM * sizeof(float);
    P.out2   = (float*)q; q += (size_t)NODES * HD * sizeof(float);
    P.tE     = (float*)q; q += (size_t)NEDGE * HD * sizeof(float);
    P.elist2 = (int*)q;   q += (size_t)NODES * ECAP * sizeof(int);
    P.Wg     = (float*)q; q += DIM * HD * sizeof(float);
    P.alpha  = (float*)q; q += sizeof(float);
    P.bg     = (float*)q; q += HD * sizeof(float);
    P.attO   = (float*)q; q += 4 * HD * sizeof(float);
    P.attg   = (float*)q; q += 4 * HD * sizeof(float);
    P.emask  = (int*)q;   q += NEDGE * sizeof(int);

    hipMemsetAsync(d_ws, 0, 16, stream);   // barrier counters only
    hipLaunchKernelGGL(k_fused, dim3(NBLK), dim3(256), 0, stream, P);
}

// Round 3
// 160.916 us; speedup vs baseline: 2.3630x; 2.3630x over previous
//
#include <hip/hip_runtime.h>

// Problem dims (fixed by setup_inputs)
#define NODES 8192
#define DIM   200
#define NEDGE 4096
#define DEGREE 16
#define HD    128
#define MT    8      // rows per tile in k_tail
#define ECAP  32     // per-node edge-list stride (Poisson(8); P(>32) ~ 1e-11/node)

__device__ __forceinline__ float dv_of(int cnt) {
    return 1.0f / sqrtf((float)cnt * (1.0f / 16.0f) + 1e-8f);
}

// ---- k_front: cnt zero + colsum partials (0..255) + Wg rows (256..355)
// ----          + bg (356) + text path (357..360).  No atomics, no memset needed.
__global__ void k_front(const float* __restrict__ x, const float* __restrict__ W,
                        const float* __restrict__ gnn_w, const float* __restrict__ bias,
                        const float* __restrict__ gnn_b, const float* __restrict__ text,
                        const float* __restrict__ text_w, const float* __restrict__ text_b,
                        const float* __restrict__ in_w, const float* __restrict__ in_b,
                        const float* __restrict__ aow, const float* __restrict__ aob,
                        const float* __restrict__ fgw, const float* __restrict__ fgb,
                        float* __restrict__ cpart, int* __restrict__ cnt,
                        float* __restrict__ Wg, float* __restrict__ bg,
                        float* __restrict__ attO, float* __restrict__ attg) {
    __shared__ float st[DIM];
    __shared__ float part[2][HD];
    __shared__ float vin[HD];
    int b = blockIdx.x, t = threadIdx.x;
    if (b < 256) {                       // colsum partials (atomic-free) + zero cnt
        if (t < 32) cnt[b * 32 + t] = 0;             // 256*32 == NODES
        if (t < DIM) {
            float acc = 0.f;
            int r0 = b * 32;
            for (int r = 0; r < 32; r++) acc += x[(r0 + r) * DIM + t];
            cpart[b * DIM + t] = acc;
        }
        return;
    }
    if (b < 356) {                       // Wg = W @ gnn_w, 2 rows per block
        int r = 2 * (b - 256) + (t >> 7);
        int c = t & 127;
        const float* vec = &W[r * DIM];
        float acc = 0.f;
        for (int k = 0; k < DIM; k++) acc += vec[k] * gnn_w[k * HD + c];
        Wg[r * HD + c] = acc;
        return;
    }
    if (b == 356) {                      // bg = bias @ gnn_w + gnn_b
        if (t < HD) {
            float acc = 0.f;
            for (int k = 0; k < DIM; k++) acc += bias[k] * gnn_w[k * HD + t];
            bg[t] = acc + gnn_b[t];
        }
        return;
    }
    // b in [357,361): text path for graph g (q/k/softmax dead: kv_len==1)
    int g = b - 357;
    int c = t & 127, h = t >> 7;
    if (t < DIM) st[t] = text[g * DIM + t];
    __syncthreads();
    {   // tp = text @ text_w + text_b   (k=200, split 100/100)
        float acc = 0.f;
        int k0 = h * 100;
        for (int k = k0; k < k0 + 100; k++) acc += st[k] * text_w[k * HD + c];
        part[h][c] = acc;
    }
    __syncthreads();
    if (t < HD) vin[t] = part[0][t] + part[1][t] + text_b[t];
    __syncthreads();
    {   // v = tp @ in_w[:, 2H:3H] + in_b[2H:3H]
        float acc = 0.f;
        int k0 = h * 64;
        for (int k = k0; k < k0 + 64; k++) acc += vin[k] * in_w[k * 3 * HD + 2 * HD + c];
        part[h][c] = acc;
    }
    __syncthreads();
    if (t < HD) vin[t] = part[0][t] + part[1][t] + in_b[2 * HD + t];
    __syncthreads();
    {   // attO = v @ aow + aob
        float acc = 0.f;
        int k0 = h * 64;
        for (int k = k0; k < k0 + 64; k++) acc += vin[k] * aow[k * HD + c];
        part[h][c] = acc;
    }
    __syncthreads();
    if (t < HD) {
        float ao = part[0][t] + part[1][t] + aob[t];
        attO[g * HD + t] = ao;
        vin[t] = ao;
    }
    __syncthreads();
    {   // attg = attO @ fgw[H:2H, :] + fgb
        float acc = 0.f;
        int k0 = h * 64;
        for (int k = k0; k < k0 + 64; k++) acc += vin[k] * fgw[(HD + k) * HD + c];
        part[h][c] = acc;
    }
    __syncthreads();
    if (t < HD) attg[g * HD + t] = part[0][t] + part[1][t] + fgb[t];
}

// ---- k_xwg: blocks 0..511 = out2 = x@Wg (16 rows/block, 4x2 register block)
// ----        + edge dedupe (8 edges/block, t<8); block 512 = alpha from cpart
__global__ void k_xwg(const float* __restrict__ x, const float* __restrict__ Wg,
                      const int* __restrict__ en, float* __restrict__ out2,
                      int* __restrict__ cnt, int* __restrict__ emask,
                      int* __restrict__ elist2, const float* __restrict__ cpart,
                      const float* __restrict__ gate_w, const float* __restrict__ gate_b,
                      float* __restrict__ alpha) {
    __shared__ float sx[16 * DIM];
    int t = threadIdx.x;
    if (blockIdx.x == 512) {             // alpha = sigmoid(mean(x)@gate_w + gate_b)
        __shared__ float red[256];
        float v = 0.f;
        if (t < DIM) {
            float s = 0.f;
            for (int q = 0; q < 256; q++) s += cpart[q * DIM + t];
            v = s * gate_w[t];
        }
        red[t] = v;
        __syncthreads();
        for (int o = 128; o > 0; o >>= 1) {
            if (t < o) red[t] += red[t + o];
            __syncthreads();
        }
        if (t == 0) {
            float z = red[0] / (float)NODES + gate_b[0];
            alpha[0] = 1.0f / (1.0f + expf(-z));
        }
        return;
    }
    int b = blockIdx.x;
    // edge dedupe (set semantics) + per-node counts + incident-edge lists
    if (t < 8) {
        int e = b * 8 + t;               // 512*8 == NEDGE
        int idx[DEGREE];
#pragma unroll
        for (int i = 0; i < DEGREE; i++) idx[i] = en[e * DEGREE + i];
        int mask = 0;
#pragma unroll
        for (int i = 0; i < DEGREE; i++) {
            bool uniq = true;
            for (int j = 0; j < i; j++) uniq = uniq && (idx[j] != idx[i]);
            if (uniq) {
                mask |= (1 << i);
                int slot = atomicAdd(&cnt[idx[i]], 1);   // slot doubles as list index
                if (slot < ECAP) elist2[idx[i] * ECAP + slot] = e;
            }
        }
        emask[e] = mask;
    }
    // out2 tile: 16 rows, 4 rows x 2 cols per thread (wave-uniform rg -> LDS broadcast)
    int bm = b * 16;
    const float4* x4 = (const float4*)(x + bm * DIM);
    float4* sx4 = (float4*)sx;
    for (int i = t; i < 16 * DIM / 4; i += 256) sx4[i] = x4[i];
    __syncthreads();
    int rg = t >> 6;                     // 0..3 -> rows rg*4..rg*4+3
    int c0 = t & 63;                     // cols c0 and c0+64
    float acc[4][2] = {{0.f,0.f},{0.f,0.f},{0.f,0.f},{0.f,0.f}};
    for (int k = 0; k < DIM; k++) {
        float w0 = Wg[k * HD + c0];
        float w1 = Wg[k * HD + c0 + 64];
#pragma unroll
        for (int i = 0; i < 4; i++) {
            float s = sx[(rg * 4 + i) * DIM + k];
            acc[i][0] += s * w0;
            acc[i][1] += s * w1;
        }
    }
#pragma unroll
    for (int i = 0; i < 4; i++) {
        out2[(bm + rg * 4 + i) * HD + c0]      = acc[i][0];
        out2[(bm + rg * 4 + i) * HD + c0 + 64] = acc[i][1];
    }
}

// ---- tE[e,:] = de[e] * sum_{i in uniq(e)} dv[m_i] * out2[m_i,:] ----
__global__ void k_tE(const int* __restrict__ en, const int* __restrict__ emask,
                     const int* __restrict__ cnt, const float* __restrict__ out2,
                     float* __restrict__ tE) {
    int e = blockIdx.x * 2 + (threadIdx.x >> 7);
    int c = threadIdx.x & 127;
    int m = emask[e];
    float De = (float)__popc(m) * (1.0f / 16.0f);
    float de = 1.0f / (De + 1e-8f);
    int nd[DEGREE];
#pragma unroll
    for (int i = 0; i < DEGREE; i++) nd[i] = en[e * DEGREE + i];
    float acc = 0.f;
#pragma unroll
    for (int i = 0; i < DEGREE; i++)
        if ((m >> i) & 1) acc += dv_of(cnt[nd[i]]) * out2[nd[i] * HD + c];
    tE[e * HD + c] = de * acc;
}

// ---- fused tail, 8-row tiles (1024 blocks):
// elist2 gather -> gp -> gate -> fused -> out = fused@opw + opb
__global__ void k_tail(const float* __restrict__ out2, const float* __restrict__ tE,
                       const int* __restrict__ cnt, const int* __restrict__ elist2,
                       const float* __restrict__ alpha, const float* __restrict__ bg,
                       const float* __restrict__ fgw, const float* __restrict__ attO,
                       const float* __restrict__ attg, const float* __restrict__ opw,
                       const float* __restrict__ opb, float* __restrict__ out) {
    __shared__ float sgp[MT][HD];
    __shared__ int   sid[MT][ECAP];
    __shared__ int   scount[MT];
    int bm = blockIdx.x * MT;
    int b = bm >> 11;                    // graph id (NNODE=2048, tiles don't straddle)
    int t = threadIdx.x;
    // phase 0: stage per-row edge lists into LDS (32 threads per row)
    {
        int r = t >> 5, sl = t & 31;
        int n = bm + r;
        int cc = cnt[n]; cc = cc < ECAP ? cc : ECAP;
        if (sl == 0) scount[r] = cc;
        if (sl < cc) sid[r][sl] = elist2[n * ECAP + sl];
    }
    __syncthreads();
    int c = t & 127, rg = t >> 7;
    float a = alpha[0];
    float bgc = bg[c];
    // phase 1: gp rows into LDS
#pragma unroll
    for (int i = 0; i < 4; i++) {
        int r = rg * 4 + i;
        int n = bm + r;
        int cc = scount[r];
        float hyp = 0.f;
        for (int j = 0; j < cc; j++) hyp += tE[sid[r][j] * HD + c];
        hyp *= dv_of(cnt[n]) * (1.0f / 256.0f);
        sgp[r][c] = a * out2[n * HD + c] + (1.0f - a) * hyp + bgc;
    }
    __syncthreads();
    // phase 2: gate logits (weight element reused across 4 rows)
    float ao = attO[b * HD + c];
    float ag = attg[b * HD + c];
    float acc[4] = {ag, ag, ag, ag};
    for (int j = 0; j < HD; j++) {
        float w = fgw[j * HD + c];
#pragma unroll
        for (int i = 0; i < 4; i++) acc[i] += sgp[rg * 4 + i][j] * w;
    }
    __syncthreads();
    // phase 3: fused = g*gp + (1-g)*attO, in place
#pragma unroll
    for (int i = 0; i < 4; i++) {
        int r = rg * 4 + i;
        float g = 1.0f / (1.0f + expf(-acc[i]));
        sgp[r][c] = g * sgp[r][c] + (1.0f - g) * ao;
    }
    __syncthreads();
    // phase 4: out = fused @ opw + opb (threads 0..199 own one output col)
    if (t < DIM) {
        float accO[MT];
        float ob = opb[t];
#pragma unroll
        for (int i = 0; i < MT; i++) accO[i] = ob;
        for (int j = 0; j < HD; j++) {
            float w = opw[j * DIM + t];
#pragma unroll
            for (int i = 0; i < MT; i++) accO[i] += sgp[i][j] * w;
        }
#pragma unroll
        for (int i = 0; i < MT; i++) out[(bm + i) * DIM + t] = accO[i];
    }
}

extern "C" void kernel_launch(void* const* d_in, const int* in_sizes, int n_in,
                              void* d_out, int out_size, void* d_ws, size_t ws_size,
                              hipStream_t stream) {
    const float* x      = (const float*)d_in[0];
    const float* text   = (const float*)d_in[1];
    const float* W      = (const float*)d_in[2];
    const float* bias   = (const float*)d_in[3];
    const float* gate_w = (const float*)d_in[4];
    const float* gate_b = (const float*)d_in[5];
    const float* gnn_w  = (const float*)d_in[6];
    const float* gnn_b  = (const float*)d_in[7];
    const float* text_w = (const float*)d_in[8];
    const float* text_b = (const float*)d_in[9];
    const float* in_w   = (const float*)d_in[10];
    const float* in_b   = (const float*)d_in[11];
    const float* aow    = (const float*)d_in[12];
    const float* aob    = (const float*)d_in[13];
    const float* fgw    = (const float*)d_in[14];
    const float* fgb    = (const float*)d_in[15];
    const float* opw    = (const float*)d_in[16];
    const float* opb    = (const float*)d_in[17];
    const int*   en     = (const int*)d_in[18];
    float* out = (float*)d_out;

    // Scratch layout (~8.2 MB of d_ws). Nothing needs pre-zeroing:
    // cnt zeroed in k_front; cpart/emask/elist2 fully overwritten before read.
    char* q = (char*)d_ws;
    int*   cnt    = (int*)q;   q += NODES * sizeof(int);
    float* cpart  = (float*)q; q += 256 * DIM * sizeof(float);
    float* out2   = (float*)q; q += (size_t)NODES * HD * sizeof(float);   // 4 MB
    float* tE     = (float*)q; q += (size_t)NEDGE * HD * sizeof(float);   // 2 MB
    int*   elist2 = (int*)q;   q += (size_t)NODES * ECAP * sizeof(int);   // 1 MB
    float* Wg     = (float*)q; q += DIM * HD * sizeof(float);
    float* alpha  = (float*)q; q += sizeof(float);
    float* bg     = (float*)q; q += HD * sizeof(float);
    float* attO   = (float*)q; q += 4 * HD * sizeof(float);
    float* attg   = (float*)q; q += 4 * HD * sizeof(float);
    int*   emask  = (int*)q;   q += NEDGE * sizeof(int);

    k_front<<<361, 256, 0, stream>>>(x, W, gnn_w, bias, gnn_b, text, text_w, text_b,
                                     in_w, in_b, aow, aob, fgw, fgb,
                                     cpart, cnt, Wg, bg, attO, attg);
    k_xwg<<<513, 256, 0, stream>>>(x, Wg, en, out2, cnt, emask, elist2,
                                   cpart, gate_w, gate_b, alpha);
    k_tE<<<NEDGE / 2, 256, 0, stream>>>(en, emask, cnt, out2, tE);
    k_tail<<<NODES / MT, 256, 0, stream>>>(out2, tE, cnt, elist2, alpha, bg, fgw,
                                           attO, attg, opw, opb, out);
}